// Round 11
// baseline (378.458 us; speedup 1.0000x reference)
//
#include <hip/hip_runtime.h>
#include <cmath>

#define SEQ 32
#define BB 1024
#define II 2048
#define OO 1024

typedef unsigned short ushortt;

// ---------------- build per-row active lists -> idxT column + reverse lists ----------------
__global__ void build_idx_rev(const float* __restrict__ x, int* __restrict__ cntArr,
                              int* __restrict__ rcnt, ushortt* __restrict__ rev,
                              ushortt* __restrict__ idxT) {
  int b = blockIdx.x;
  int lane = threadIdx.x;  // 64 threads = 1 wave
  __shared__ ushortt sIdx[256];
  const float* row = x + (long)b * II;
  int base = 0;
  for (int c = 0; c < II / 64; ++c) {
    float val = row[c * 64 + lane];
    unsigned long long m = __ballot(val != 0.0f);
    if (val != 0.0f) {
      int pos = base + __popcll(m & ((1ull << lane) - 1ull));
      if (pos < 256) sIdx[pos] = (ushortt)(c * 64 + lane);
    }
    base += __popcll(m);
  }
  int cnt = base < 256 ? base : 256;
  if (lane == 0) cntArr[b] = cnt;
  __syncthreads();
  for (int j = lane; j < 256; j += 64) {
    ushortt iv = (j < cnt) ? sIdx[j] : (ushortt)0;
    idxT[(long)j * BB + b] = iv;  // pad entries never read (snn uses exact cnt)
    if (j < cnt) {
      int pos = atomicAdd(&rcnt[iv], 1);
      if (pos < 128) rev[((long)iv << 7) + pos] = (ushortt)b;
    }
  }
}

// ---------------- dual transpose for z/v ([O][B] -> [B][O]) ----------------
__global__ void transpose2_f32(const float* __restrict__ zC, const float* __restrict__ vC,
                               float* __restrict__ oz, float* __restrict__ ov) {
  __shared__ float t[32][33];
  const float* src = blockIdx.z ? vC : zC;
  float* dst = blockIdx.z ? ov : oz;
  int c0 = blockIdx.x * 32, r0 = blockIdx.y * 32;
  int tx = threadIdx.x, ty = threadIdx.y;
#pragma unroll
  for (int k = 0; k < 4; k++)
    t[ty + k * 8][tx] = src[(long)(r0 + ty + k * 8) * BB + c0 + tx];
  __syncthreads();
#pragma unroll
  for (int k = 0; k < 4; k++)
    dst[(long)(c0 + ty + k * 8) * OO + r0 + tx] = t[tx][ty + k * 8];
}

// ---------------- full 32-step sim, one block per column ----------------
// LDS: wL[2048] (8 KB) + sc[3072] scatter/scratch (12 KB) + flags = ~20.5 KB.
// A and n in registers (static indexing only — no scratch). 2 barriers per quiet
// step: parity flag slots make the end-of-step barrier unnecessary (consume-zero
// of sc at step t is separated from step t+1's scatter by barrier 1 of t+1).
// S0/Snu computed in-kernel (fp32 j-order: bit-identical to prior s0_kernel).
__global__ __launch_bounds__(256, 4) void snn_kernel(
    const float* __restrict__ x, const float* __restrict__ w,
    const float* __restrict__ bias, const int* __restrict__ rcnt,
    const ushortt* __restrict__ idxT, const int* __restrict__ cntArr,
    const ushortt* __restrict__ rev,
    float* __restrict__ zC, float* __restrict__ vC, float* __restrict__ outw,
    float dec) {
  int o = blockIdx.x, tid = threadIdx.x, lane = tid & 63;
  __shared__ float wL[II];
  __shared__ float sc[3072];  // quiet: Sfix|SnuD|SAD (1024 each); spike: mL(2048)+sList(1024)
  __shared__ int sFlagBuf[2], cFlagBuf[2], sCnt;
  float* Sfix = sc;
  float* SnuD = sc + 1024;
  float* SAD = sc + 2048;
  float* mL = sc;                    // alias (spike phase)
  int* sList = (int*)(sc + 2048);    // alias (spike phase)

  float Ar[8], nr[8];
#pragma unroll
  for (int q = 0; q < 8; ++q) {
    int i = q * 256 + tid;
    wL[i] = w[(long)o * II + i];
    Ar[q] = 0.f;
    nr[q] = (float)rcnt[i];
  }
  int cntb[4];
  double S[4];
  float Snu[4], SA[4], v4[4], zo4[4], vo4[4];
#pragma unroll
  for (int k = 0; k < 4; ++k) {
    cntb[k] = cntArr[k * 256 + tid];
    SA[k] = 0.f; v4[k] = 0.f; zo4[k] = 0.f; vo4[k] = 0.f;
  }
  if (tid == 0) { sFlagBuf[0] = 0; sFlagBuf[1] = 0; cFlagBuf[0] = 0; cFlagBuf[1] = 0; }
  // n-dump for Snu init (sc[0..2047])
#pragma unroll
  for (int q = 0; q < 8; ++q) sc[q * 256 + tid] = nr[q];
  __syncthreads();
  float bo = bias[o];
  // init gather: S (fp32 j-order sum, cast to double — matches prior s0_kernel), Snu
#pragma unroll
  for (int k = 0; k < 4; ++k) {
    int b = k * 256 + tid;
    float acc = 0.f, sn = 0.f;
    int cb = cntb[k];
    for (int j = 0; j < cb; ++j) {
      int idx = idxT[(long)j * BB + b];
      acc += wL[idx];
      sn += sc[idx];
    }
    S[k] = (double)acc;
    Snu[k] = sn;
  }
  __syncthreads();
  // zero the scatter area (invariant: all 3072 zero outside active use)
#pragma unroll
  for (int q = 0; q < 12; ++q) sc[q * 256 + tid] = 0.f;

  unsigned clipped = 0;
  float p = 1.f, u = 1.f;
  for (int t = 0; t < SEQ; ++t) {
    p *= dec; u *= dec; u += 1.f;
    float spre = u - p;
    // phase A (registers only)
    int local = 0;
    float zk[4];
#pragma unroll
    for (int k = 0; k < 4; ++k) {
      float zin = (float)S[k] + bo;
      float nv = v4[k] * dec + zin;
      float z = (nv >= 1.f) ? 1.f : 0.f;
      nv = nv * (1.f - z);
      v4[k] = nv; zk[k] = z;
      if (z != 0.f) local = 1;
    }
    if (local) sFlagBuf[t & 1] = 1;
    __syncthreads();  // b1
    int spk = sFlagBuf[t & 1];
    if (tid == 0) { sFlagBuf[(t + 1) & 1] = 0; cFlagBuf[(t + 1) & 1] = 0; }  // dead slot reset

    if (!spk) {
      // phase B: quiet per-i update (w in LDS, A/n in regs) + cooperative clip scatter
      float wv8[8];
#pragma unroll
      for (int q = 0; q < 8; ++q) wv8[q] = wL[q * 256 + tid];
#pragma unroll
      for (int q = 0; q < 8; ++q) {
        int i = q * 256 + tid;
        bool already = (clipped >> q) & 1u;
        float n = 0.f, atn = 0.f, fix = 0.f;
        bool cl = false;
        if (!already) {
          n = nr[q];
          atn = dec * Ar[q];
          float dw = -(1e-3f * (p * n + atn));
          float wold = wv8[q];
          float pre = wold + dw;
          float wv = fminf(fmaxf(pre, -1.f), 1.f);
          cl = (pre <= -1.f);
          if (cl) {
            clipped |= 1u << q;
            fix = (-1.f - wold) - dw;
            Ar[q] = 0.f;
          } else {
            Ar[q] = atn;
          }
          wL[i] = wv;
        }
        unsigned long long m = __ballot(cl);
        if (m) {
          if (lane == 0) cFlagBuf[t & 1] = 1;
          while (m) {
            int src = __builtin_ctzll(m);
            m &= m - 1;
            int ii = __shfl(i, src);
            float fx = __shfl(fix, src);
            float mn = -__shfl(n, src);
            float ma = -__shfl(atn, src);
            int rc = rcnt[ii];
            const ushortt* rp = rev + ((long)ii << 7);
            for (int r = lane; r < rc; r += 64) {
              int bb = rp[r];
              atomicAdd(&Sfix[bb], fx);
              atomicAdd(&SnuD[bb], mn);
              atomicAdd(&SAD[bb], ma);
            }
          }
        }
      }
      __syncthreads();  // b2
      // phase C: apply bulk + corrections, restore zeros (safe: next writes after b1(t+1))
      int cf = cFlagBuf[t & 1];
      float coefP = 1e-3f * p;
      if (cf) {
#pragma unroll
        for (int k = 0; k < 4; ++k) {
          int b = k * 256 + tid;
          S[k] = S[k] - (double)coefP * (double)Snu[k]
                      - (double)1e-3f * (double)(dec * SA[k])
                      + (double)Sfix[b];
          SA[k] = dec * SA[k] + SAD[b];
          Snu[k] = Snu[k] + SnuD[b];
          Sfix[b] = 0.f; SnuD[b] = 0.f; SAD[b] = 0.f;
        }
      } else {
#pragma unroll
        for (int k = 0; k < 4; ++k) {
          S[k] = S[k] - (double)coefP * (double)Snu[k]
                      - (double)1e-3f * (double)(dec * SA[k]);
          SA[k] = dec * SA[k];
        }
      }
    } else {
      // spike step (rare): exact update, then re-gather S/SA/Snu via dumps
      if (tid == 0) sCnt = 0;
      __syncthreads();
#pragma unroll
      for (int k = 0; k < 4; ++k)
        if (zk[k] != 0.f) { int pos = atomicAdd(&sCnt, 1); sList[pos] = k * 256 + tid; }
      __syncthreads();
      int ns = sCnt;
      // mL starts at zero (scatter-area invariant)
      for (int s = 0; s < ns; ++s) {
        int bsp = sList[s];
#pragma unroll
        for (int q = 0; q < 8; ++q) {
          int i = q * 256 + tid;
          if (x[(long)bsp * II + i] != 0.f) mL[i] += 1.f;
        }
      }
      __syncthreads();
      float cv = (float)ns;
      float wv8[8];
#pragma unroll
      for (int q = 0; q < 8; ++q) wv8[q] = wL[q * 256 + tid];
#pragma unroll
      for (int q = 0; q < 8; ++q) {
        int i = q * 256 + tid;
        float mt = mL[i];
        float atn = dec * Ar[q] + mt;
        float n = nr[q];
        float dw = 1e-3f * (p * cv + spre * mt) - 1e-3f * (p * n + atn);
        float pre = wv8[q] + dw;
        float wv = fminf(fmaxf(pre, -1.f), 1.f);
        bool cl = (pre <= -1.f);
        if (cl) clipped |= 1u << q; else clipped &= ~(1u << q);
        wL[i] = wv;
        Ar[q] = cl ? 0.f : atn;
      }
      __syncthreads();  // wL final; mL dead
      // dump masked A, gather S (f64) + SA
#pragma unroll
      for (int q = 0; q < 8; ++q) mL[q * 256 + tid] = Ar[q];  // clipped -> 0 already
      __syncthreads();
#pragma unroll
      for (int k = 0; k < 4; ++k) {
        int b = k * 256 + tid;
        double s = 0.0; float sa = 0.f;
        int cb = cntb[k];
        for (int j = 0; j < cb; ++j) {
          int idx = idxT[(long)j * BB + b];
          s += (double)wL[idx];
          sa += mL[idx];
        }
        S[k] = s; SA[k] = sa;
      }
      __syncthreads();
      // dump masked n, gather Snu
#pragma unroll
      for (int q = 0; q < 8; ++q) mL[q * 256 + tid] = ((clipped >> q) & 1u) ? 0.f : nr[q];
      __syncthreads();
#pragma unroll
      for (int k = 0; k < 4; ++k) {
        int b = k * 256 + tid;
        float sn = 0.f;
        int cb = cntb[k];
        for (int j = 0; j < cb; ++j) sn += mL[idxT[(long)j * BB + b]];
        Snu[k] = sn;
      }
      __syncthreads();
      // restore scatter-area zeros (visible to next phase B via b1(t+1))
#pragma unroll
      for (int q = 0; q < 12; ++q) sc[q * 256 + tid] = 0.f;
    }

    if (t == SEQ - 1) {
#pragma unroll
      for (int k = 0; k < 4; ++k) { zo4[k] = zk[k]; vo4[k] = v4[k]; }
    }
  }

  __syncthreads();
  // coalesced outputs: w row-major; z/v column-major staging (transposed after)
#pragma unroll
  for (int q = 0; q < 8; ++q) outw[(long)o * II + q * 256 + tid] = wL[q * 256 + tid];
#pragma unroll
  for (int k = 0; k < 4; ++k) {
    int b = k * 256 + tid;
    zC[(long)o * BB + b] = zo4[k];
    vC[(long)o * BB + b] = vo4[k];
  }
}

extern "C" void kernel_launch(void* const* d_in, const int* in_sizes, int n_in,
                              void* d_out, int out_size, void* d_ws, size_t ws_size,
                              hipStream_t stream) {
  const float* x = (const float*)d_in[0];     // [B, I] {0,1} fp32
  const float* w = (const float*)d_in[1];     // [O, I] fp32
  const float* bias = (const float*)d_in[2];  // [O]
  float* out = (float*)d_out;                 // z[B,O] | v[B,O] | w[O,I]

  char* ws = (char*)d_ws;
  int* cntArr = (int*)(ws + 0);            // 4 KB
  ushortt* idxT = (ushortt*)(ws + 4096);   // 512 KB
  int* rcnt = (int*)(ws + 528384);         // 8 KB
  ushortt* rev = (ushortt*)(ws + 536576);  // 512 KB
  float* zC = (float*)(ws + 1060864);      // 4 MB
  float* vC = (float*)(ws + 5255168);      // 4 MB

  hipMemsetAsync(rcnt, 0, II * sizeof(int), stream);
  build_idx_rev<<<BB, 64, 0, stream>>>(x, cntArr, rcnt, rev, idxT);

  const float dec = (float)exp(-0.05);  // shared decay (pre/post/mem)

  snn_kernel<<<OO, 256, 0, stream>>>(x, w, bias, rcnt, idxT, cntArr, rev,
                                     zC, vC, out + 2 * BB * OO, dec);

  // z, v: [O][B] -> [B][O]
  transpose2_f32<<<dim3(BB / 32, OO / 32, 2), dim3(32, 8), 0, stream>>>(zC, vC, out, out + BB * OO);
}